// Round 10
// baseline (673.143 us; speedup 1.0000x reference)
//
#include <hip/hip_runtime.h>

#define DEV __device__ __forceinline__

// ---- input plane sizes (complex element counts; imag plane at +PL) ----
#define PL_VU 12288
#define PL_UU 131072
#define PL_WU 8192
#define PL_GD 196608
#define PL_UD 16384
#define PL_WD 8192
#define PL_Z  196608
#define PL_HU 262144
#define PL_HD 262144
#define PL_P  16384
#define PL_GU 196608
#define PL_F  131072
#define PL_VD 12288
#define PL_J  4194304

// ---- intermediate plane sizes ----
#define SP_T   98304    // [96,8,128]
#define SP_PPH 32768    // [16,16,128]
#define SP_Q   196608   // [96,16,128] / [16,96,128]
#define SP_H2  262144   // [128,16,128]

// ---- workspace float offsets. complex buf: re at off+idx, im at off+plane+idx ----
#define W_T1   0
#define W_T2   196608
#define W_T3   393216
#define W_PPH  589824
#define W_VF   655360
#define W_M1   851968
#define W_M1C  1048576
#define W_M2   1245184
#define W_M2C  1441792
#define W_M3   1638400
#define W_QT   1835008
#define W_G2   2228224
#define W_H2   2621440
#define W_U2   3145728
#define W_TL   3538944
#define W_N1   3932160
#define W_R    4325376
#define W_MATS 4718592  // 9 x [2,96,96] (18432 each, plane 9216): A1,B1,C1,A2,B2,C2,A3,B3,C3
#define W_B11  4884480  // [96,128] pl 12288
#define W_B12  4909056  // [128,96] pl 12288
#define W_B21  4933632
#define W_B22  4958208
#define W_C1O  4982784  // 12*48*48
#define W_C2O  5010432  // 8*24*24
#define W_C3O  5015040  // 864
#define W_F1O  5015904  // 1000
#define W_F2O  5016904  // 700
// total 5017604 floats = 20.1 MB of d_ws

struct Ins {
  const float *VU,*UU,*WU,*GD,*UD,*WD,*Z,*HU,*HD,*P,*GU,*F,*VD,*J;
};

// =================== stage A: T1,T2,T3,PPH,VF ===================
// segments: T1 384, T2 384, T3 384, PPH 128, VF 384  => 1664 blocks
__global__ __launch_bounds__(256) void stageA(Ins in, float* __restrict__ ws) {
  int b = blockIdx.x, tid = threadIdx.x;
  if (b < 384) {                // T1[m,u,k] = sum_n conj(VU[n,m]) UU[n,u,k]
    int idx = b*256 + tid;
    int k = idx & 127, u = (idx >> 7) & 7, m = idx >> 10;
    float ar=0, ai=0;
    for (int n=0;n<128;++n) {
      float vr = in.VU[n*96+m], vi = in.VU[PL_VU+n*96+m];
      int iu = (n*8+u)*128+k;
      float ur = in.UU[iu], ui = in.UU[PL_UU+iu];
      ar += vr*ur + vi*ui; ai += vr*ui - vi*ur;
    }
    ws[W_T1+idx]=ar; ws[W_T1+SP_T+idx]=ai;
  } else if (b < 768) {         // T2[m,d,l] = sum_n conj(GD[n,m,l]) UD[n,d,l]
    int idx = (b-384)*256 + tid;
    int l = idx & 127, d = (idx >> 7) & 7, m = idx >> 10;
    float ar=0, ai=0;
    for (int n=0;n<16;++n) {
      int ig = (n*96+m)*128+l, iu = (n*8+d)*128+l;
      float gr = in.GD[ig], gi = in.GD[PL_GD+ig];
      float ur = in.UD[iu], ui = in.UD[PL_UD+iu];
      ar += gr*ur + gi*ui; ai += gr*ui - gi*ur;
    }
    ws[W_T2+idx]=ar; ws[W_T2+SP_T+idx]=ai;
  } else if (b < 1152) {        // T3 = same with Z
    int idx = (b-768)*256 + tid;
    int l = idx & 127, d = (idx >> 7) & 7, m = idx >> 10;
    float ar=0, ai=0;
    for (int n=0;n<16;++n) {
      int ig = (n*96+m)*128+l, iu = (n*8+d)*128+l;
      float gr = in.Z[ig], gi = in.Z[PL_Z+ig];
      float ur = in.UD[iu], ui = in.UD[PL_UD+iu];
      ar += gr*ur + gi*ui; ai += gr*ui - gi*ur;
    }
    ws[W_T3+idx]=ar; ws[W_T3+SP_T+idx]=ai;
  } else if (b < 1280) {        // PPH[a,b,k] = sum_u P[a,u,k] conj(P[b,u,k])
    int idx = (b-1152)*256 + tid;
    int k = idx & 127, bb = (idx >> 7) & 15, a = idx >> 11;
    float ar=0, ai=0;
    for (int u=0;u<8;++u) {
      int ia = (a*8+u)*128+k, ib = (bb*8+u)*128+k;
      float pr = in.P[ia], pi = in.P[PL_P+ia];
      float qr = in.P[ib], qi = in.P[PL_P+ib];
      ar += pr*qr + pi*qi; ai += pi*qr - pr*qi;
    }
    ws[W_PPH+idx]=ar; ws[W_PPH+SP_PPH+idx]=ai;
  } else {                      // VF[f,d,l] = sum_a VD[f,a] F[a,d,l]
    int idx = (b-1280)*256 + tid;
    int l = idx & 127, d = (idx >> 7) & 7, f = idx >> 10;
    float ar=0, ai=0;
    for (int a=0;a<128;++a) {
      float vr = in.VD[f*128+a], vi = in.VD[PL_VD+f*128+a];
      int ix = (a*8+d)*128+l;
      float fr = in.F[ix], fi = in.F[PL_F+ix];
      ar += vr*fr - vi*fi; ai += vr*fi + vi*fr;
    }
    ws[W_VF+idx]=ar; ws[W_VF+SP_T+idx]=ai;
  }
}

// ============ generic per-k inner product: out[m,n,k]=sum_e opA(A[m,e,k])*opB(B[..]) ============
template<bool CONJA, bool CONJB, bool BENK, int N, int E>
DEV void inner_seg(const float* __restrict__ A, int Apl,
                   const float* __restrict__ B, int Bpl,
                   float* __restrict__ O, int Opl, int idx) {
  int k = idx & 127;
  int n = (idx >> 7) % N;
  int m = idx / (128*N);
  float ar=0, ai=0;
  #pragma unroll
  for (int e=0;e<E;++e) {
    int ia = (m*E+e)*128+k;
    float xr = A[ia], xi = A[Apl+ia];
    if (CONJA) xi = -xi;
    int ib = BENK ? (e*N+n)*128+k : (n*E+e)*128+k;
    float yr = B[ib], yi = B[Bpl+ib];
    if (CONJB) yi = -yi;
    ar += xr*yr - xi*yi; ai += xr*yi + xi*yr;
  }
  O[idx]=ar; O[Opl+idx]=ai;
}

// =================== stage B: M1,M1c,M2,M2c,M3,Qt,G2,H2 + zero R ===================
// segments: 5x384 (M*), 768 (Qt), 768 (G2), 1024 (H2), 384 (zeroR) => 4864 blocks
__global__ __launch_bounds__(256) void stageB(Ins in, float* __restrict__ ws) {
  int b = blockIdx.x, tid = threadIdx.x;
  if (b < 384)       inner_seg<false,false,true ,8, 8>(ws+W_T1,SP_T, in.WU,PL_WU, ws+W_M1, SP_T, b*256+tid);
  else if (b < 768)  inner_seg<false,true ,false,8, 8>(ws+W_T1,SP_T, in.WU,PL_WU, ws+W_M1C,SP_T, (b-384)*256+tid);
  else if (b < 1152) inner_seg<false,false,true ,8, 8>(ws+W_T2,SP_T, in.WD,PL_WD, ws+W_M2, SP_T, (b-768)*256+tid);
  else if (b < 1536) inner_seg<false,true ,false,8, 8>(ws+W_T2,SP_T, in.WD,PL_WD, ws+W_M2C,SP_T, (b-1152)*256+tid);
  else if (b < 1920) inner_seg<false,false,true ,8, 8>(ws+W_T3,SP_T, in.WD,PL_WD, ws+W_M3, SP_T, (b-1536)*256+tid);
  else if (b < 2688) inner_seg<true ,false,false,16,16>(in.GU,PL_GU, ws+W_PPH,SP_PPH, ws+W_QT, SP_Q,  (b-1920)*256+tid);  // Qt[f,a,k]
  else if (b < 3456) inner_seg<false,true ,false,16,16>(in.GU,PL_GU, ws+W_PPH,SP_PPH, ws+W_G2, SP_Q,  (b-2688)*256+tid);  // G2[f,b,k] (PPH Hermitian)
  else if (b < 4480) inner_seg<false,true ,false,16,16>(in.HU,PL_HU, ws+W_PPH,SP_PPH, ws+W_H2, SP_H2, (b-3456)*256+tid);  // H2[n,b,k]
  else {  // zero R region (ws is poisoned 0xAA before every call; kR accumulates with atomics)
    int idx = (b-4480)*256 + tid;
    ((float4*)(ws+W_R))[idx] = make_float4(0.f,0.f,0.f,0.f);
  }
}

// =================== stage C: U2, TL, N1 ===================
__global__ __launch_bounds__(256) void stageC(float* __restrict__ ws, Ins in) {
  int b = blockIdx.x, tid = threadIdx.x;
  if (b < 768)        inner_seg<false,true,false,16,8>(ws+W_M2, SP_T, in.UD,PL_UD, ws+W_U2, SP_Q, b*256+tid);
  else if (b < 1536)  inner_seg<false,true,false,16,8>(ws+W_M3, SP_T, in.UD,PL_UD, ws+W_TL, SP_Q, (b-768)*256+tid);
  else                inner_seg<false,true,false,16,8>(ws+W_M1C,SP_T, in.P, PL_P,  ws+W_N1, SP_Q, (b-1536)*256+tid);
}

// =================== kR: R[n,f,l] = sum_{a,k} J[n,a,k,l] * Qt[f,a,k] ===================
// grid 512 = 16 n x 8 kc(16 k) x 2 lh(64 l) x 2 ah(8 a); block 256 = 8 f-groups(12 f) x 32 lanes(2 l).
// v4: J prefetch in 4-kk chunks (2 x (4+4) float2 = 32 VGPR) so live set (~105) fits the
// observed 128-VGPR allocation with ZERO spill (round-8: 64-reg J buffer spilled ~500MB scratch).
// J read exactly once globally; qt double-buffered in LDS (24 KB), 1 barrier per a.
__global__ __launch_bounds__(256, 2) void kR(Ins in, float* __restrict__ ws) {
  int bid = blockIdx.x;
  int n  = bid >> 5;
  int kc = (bid >> 2) & 7;
  int lh = (bid >> 1) & 1;
  int ah = bid & 1;
  int tid = threadIdx.x;
  int g    = tid >> 5;            // f-group 0..7 (12 f each)
  int lane = tid & 31;
  int l0 = lh*64 + lane*2;
  int k0 = kc*16;
  int a0 = ah*8;

  __shared__ float2 qt[2][1536];  // [buf][f*16+kk], 24 KB

  float accr[12][2], acci[12][2];
  #pragma unroll
  for (int j=0;j<12;++j) { accr[j][0]=accr[j][1]=acci[j][0]=acci[j][1]=0.f; }

  const float* Jn = in.J + n*262144 + k0*128 + l0;
  float2 jrA[4], jiA[4], jrB[4], jiB[4];

// step s in [0,32): a = a0 + (s>>2), kk-chunk c = s&3 (4 kk per chunk, offset c*512)
#define LOADJ(JR, JI, s) { const float* Jb = Jn + (a0 + ((s)>>2))*16384 + ((s)&3)*512; \
  _Pragma("unroll") for (int kk=0;kk<4;++kk) { \
    JR[kk] = *(const float2*)(Jb + kk*128); \
    JI[kk] = *(const float2*)(Jb + PL_J + kk*128); } }

#define STAGEQ(buf, a) { _Pragma("unroll") for (int i=0;i<6;++i) { \
    int t = tid + i*256; int f = t >> 4, kk = t & 15; \
    int qi = (f*16 + (a))*128 + k0 + kk; \
    qt[buf][t] = make_float2(ws[W_QT+qi], ws[W_QT+SP_Q+qi]); } }

#define COMPUTE(JR, JI, CUR, C) { _Pragma("unroll") for (int kk=0;kk<4;++kk) { \
    _Pragma("unroll") for (int j=0;j<12;++j) { \
      float2 q = qt[CUR][(g*12+j)*16 + (C)*4 + kk]; \
      accr[j][0] += JR[kk].x*q.x - JI[kk].x*q.y; \
      acci[j][0] += JR[kk].x*q.y + JI[kk].x*q.x; \
      accr[j][1] += JR[kk].y*q.x - JI[kk].y*q.y; \
      acci[j][1] += JR[kk].y*q.y + JI[kk].y*q.x; } } }

  STAGEQ(0, a0)
  LOADJ(jrA, jiA, 0)
  for (int ia=0; ia<8; ++ia) {
    int cur = ia & 1;
    int s0 = ia*4;
    __syncthreads();                 // qt[cur] staged; fences overwrite of qt[cur^1] below
    if (ia < 7) STAGEQ(cur^1, a0+ia+1)
    LOADJ(jrB, jiB, s0+1)
    COMPUTE(jrA, jiA, cur, 0)
    LOADJ(jrA, jiA, s0+2)
    COMPUTE(jrB, jiB, cur, 1)
    LOADJ(jrB, jiB, s0+3)
    COMPUTE(jrA, jiA, cur, 2)
    if (ia < 7) LOADJ(jrA, jiA, s0+4)
    COMPUTE(jrB, jiB, cur, 3)
  }

  #pragma unroll
  for (int j=0;j<12;++j) {
    int f = g*12+j;
    int o = (n*96+f)*128 + l0;
    atomicAdd(&ws[W_R + o],            accr[j][0]);
    atomicAdd(&ws[W_R + o + 1],        accr[j][1]);
    atomicAdd(&ws[W_R + SP_Q + o],     acci[j][0]);
    atomicAdd(&ws[W_R + SP_Q + o + 1], acci[j][1]);
  }
#undef LOADJ
#undef STAGEQ
#undef COMPUTE
}

// ============ generic flat contraction: C[i,j] = scale*sum_{o,c} A[i,o,c]*opB(B) ============
template<bool CONJB, bool OJC>
DEV void outer_tile(const float* __restrict__ A, int Apl,
                    const float* __restrict__ B, int Bpl,
                    float* __restrict__ C, int Cpl,
                    int J, int O, float scale, int tile) {
  __shared__ float As[16][33], Aip[16][33], Bs[16][33], Bip[16][33];
  int tj = J >> 4;
  int ti_ = tile / tj, tj_ = tile % tj;
  int tx = threadIdx.x & 15, ty = threadIdx.x >> 4;
  float ar=0, ai=0;
  int r0 = threadIdx.x >> 5, c = threadIdx.x & 31;
  for (int o=0;o<O;++o) {
    for (int cc=0;cc<128;cc+=32) {
      __syncthreads();
      #pragma unroll
      for (int rr=r0; rr<16; rr+=8) {
        int aidx = ((ti_*16+rr)*O+o)*128+cc+c;
        As[rr][c]=A[aidx]; Aip[rr][c]=A[Apl+aidx];
        int brow = tj_*16+rr;
        int bidx = OJC ? (o*J+brow)*128+cc+c : (brow*O+o)*128+cc+c;
        Bs[rr][c]=B[bidx]; Bip[rr][c]=B[Bpl+bidx];
      }
      __syncthreads();
      #pragma unroll
      for (int q=0;q<32;++q) {
        float xr=As[ty][q], xi=Aip[ty][q];
        float yr=Bs[tx][q], yi=Bip[tx][q];
        if (CONJB) { ar += xr*yr + xi*yi; ai += xi*yr - xr*yi; }
        else       { ar += xr*yr - xi*yi; ai += xr*yi + xi*yr; }
      }
    }
  }
  int i = ti_*16+ty, j = tj_*16+tx;
  C[i*J+j] = scale*ar; C[Cpl+i*J+j] = scale*ai;
}

// =================== stage D: all flat contractions (516 blocks) ===================
__global__ __launch_bounds__(256) void stageD(Ins in, float* __restrict__ ws) {
  int b = blockIdx.x;
  if (b < 36)        outer_tile<true ,false>(ws+W_M1, SP_T,  ws+W_T1, SP_T,  ws+W_MATS+0*18432, 9216, 96, 8,  1.f, b);      // A1
  else if (b < 72)   outer_tile<true ,false>(ws+W_M2, SP_T,  ws+W_T2, SP_T,  ws+W_MATS+3*18432, 9216, 96, 8,  1.f, b-36);   // A2
  else if (b < 108)  outer_tile<true ,false>(ws+W_M3, SP_T,  ws+W_T3, SP_T,  ws+W_MATS+6*18432, 9216, 96, 8,  1.f, b-72);   // A3
  else if (b < 144)  outer_tile<true ,false>(ws+W_G2, SP_Q,  in.GU,   PL_GU, ws+W_MATS+2*18432, 9216, 96, 16, 1.f, b-108);  // C1
  else if (b < 180)  outer_tile<true ,false>(ws+W_G2, SP_Q,  in.GU,   PL_GU, ws+W_MATS+8*18432, 9216, 96, 16, 1.f, b-144);  // C3=C1
  else if (b < 216)  outer_tile<true ,false>(ws+W_VF, SP_T,  ws+W_VF, SP_T,  ws+W_MATS+5*18432, 9216, 96, 8,  1.f, b-180);  // C2
  else if (b < 264)  outer_tile<true ,false>(ws+W_M1, SP_T,  in.UU,   PL_UU, ws+W_B11, 12288, 128, 8,  1.f, b-216);         // B1_1[m,n]
  else if (b < 312)  outer_tile<true ,false>(ws+W_H2, SP_H2, in.GU,   PL_GU, ws+W_B12, 12288,  96, 16, 1.f, b-264);         // B1_2[n,f]
  else if (b < 348)  outer_tile<true ,false>(ws+W_N1, SP_Q,  in.GU,   PL_GU, ws+W_MATS+1*18432, 9216, 96, 16, 1.f, b-312);  // B1_3 (pre for B1)
  else if (b < 396)  outer_tile<false,true >(ws+W_U2, SP_Q,  in.HD,   PL_HD, ws+W_B21, 12288, 128, 16, 1.f, b-348);         // B2_1[m,t]
  else if (b < 444)  outer_tile<true ,false>(in.F,    PL_F,  ws+W_VF, SP_T,  ws+W_B22, 12288,  96, 8,  1.f, b-396);         // B2_2[a,f]
  else if (b < 480)  outer_tile<true ,false>(ws+W_M2C,SP_T,  ws+W_VF, SP_T,  ws+W_MATS+4*18432, 9216, 96, 8,  1.f, b-444);  // B2_3 (pre for B2)
  else               outer_tile<false,true >(ws+W_TL, SP_Q,  ws+W_R,  SP_Q,  ws+W_MATS+7*18432, 9216, 96, 16,-1.f, b-480);  // B3
}

// =================== stage E: B1 = B1_3 - B1_1@B1_2 ; B2 = B2_3 - B2_1@B2_2 ===================
__global__ __launch_bounds__(256) void stageE(float* __restrict__ ws) {
  int idx = blockIdx.x*256 + threadIdx.x;
  int seg = idx / 9216;
  int t = idx % 9216;
  int m = t / 96, f = t % 96;
  const float* A = ws + (seg ? W_B21 : W_B11);
  const float* B = ws + (seg ? W_B22 : W_B12);
  float* C = ws + W_MATS + (seg ? 4 : 1)*18432;
  float ar = C[t], ai = C[9216+t];
  for (int n=0;n<128;++n) {
    float xr = A[m*128+n], xi = A[12288+m*128+n];
    float yr = B[n*96+f],  yi = B[12288+n*96+f];
    ar -= xr*yr - xi*yi;
    ai -= xr*yi + xi*yr;
  }
  C[t] = ar; C[9216+t] = ai;
}

// =================== conv (2x2, stride 2, relu) ===================
__global__ __launch_bounds__(256) void convk(const float* __restrict__ x, const float* __restrict__ w,
                      const float* __restrict__ bias, float* __restrict__ out,
                      int IC, int IW, int OC, int OW) {
  int idx = blockIdx.x*256 + threadIdx.x;
  int total = OC*OW*OW;
  if (idx >= total) return;
  int ow = idx % OW, oh = (idx/OW) % OW, oc = idx/(OW*OW);
  float acc = bias[oc];
  const float* wk = w + oc*IC*4;
  for (int ic=0; ic<IC; ++ic) {
    const float* xp = x + ic*IW*IW + (oh*2)*IW + ow*2;
    acc += xp[0]*wk[0] + xp[1]*wk[1] + xp[IW]*wk[2] + xp[IW+1]*wk[3];
    wk += 4;
  }
  out[idx] = fmaxf(acc, 0.f);
}

// =================== fc (wave per output, relu) ===================
__global__ __launch_bounds__(256) void fck(const float* __restrict__ W, const float* __restrict__ b,
                    const float* __restrict__ x, float* __restrict__ out,
                    int nout, int nin) {
  int wave = (blockIdx.x*256 + threadIdx.x) >> 6;
  int lane = threadIdx.x & 63;
  if (wave >= nout) return;
  float acc = 0.f;
  const float* Wr = W + (long)wave*nin;
  for (int c = lane; c < nin; c += 64) acc += Wr[c]*x[c];
  #pragma unroll
  for (int off=32; off; off>>=1) acc += __shfl_down(acc, off, 64);
  if (lane==0) out[wave] = fmaxf(acc + b[wave], 0.f);
}

extern "C" void kernel_launch(void* const* d_in, const int* in_sizes, int n_in,
                              void* d_out, int out_size, void* d_ws, size_t ws_size,
                              hipStream_t stream) {
  Ins in;
  in.VU=(const float*)d_in[0];  in.UU=(const float*)d_in[1];  in.WU=(const float*)d_in[2];
  in.GD=(const float*)d_in[3];  in.UD=(const float*)d_in[4];  in.WD=(const float*)d_in[5];
  in.Z =(const float*)d_in[6];  in.HU=(const float*)d_in[7];  in.HD=(const float*)d_in[8];
  in.P =(const float*)d_in[9];  in.GU=(const float*)d_in[10]; in.F =(const float*)d_in[11];
  in.VD=(const float*)d_in[12]; in.J =(const float*)d_in[13];
  float* ws = (float*)d_ws;

  stageA<<<1664,256, 0, stream>>>(in, ws);
  stageB<<<4864,256, 0, stream>>>(in, ws);
  stageC<<<2304,256, 0, stream>>>(ws, in);
  kR    <<<512, 256, 0, stream>>>(in, ws);
  stageD<<<516, 256, 0, stream>>>(in, ws);
  stageE<<<72,  256, 0, stream>>>(ws);
  convk <<<108, 256, 0, stream>>>(ws+W_MATS, (const float*)d_in[14], (const float*)d_in[15], ws+W_C1O, 18, 96, 12, 48);
  convk <<<18,  256, 0, stream>>>(ws+W_C1O,  (const float*)d_in[16], (const float*)d_in[17], ws+W_C2O, 12, 48, 8, 24);
  convk <<<4,   256, 0, stream>>>(ws+W_C2O,  (const float*)d_in[18], (const float*)d_in[19], ws+W_C3O, 8, 24, 6, 12);
  fck   <<<250, 256, 0, stream>>>((const float*)d_in[20], (const float*)d_in[21], ws+W_C3O, ws+W_F1O, 1000, 864);
  fck   <<<175, 256, 0, stream>>>((const float*)d_in[22], (const float*)d_in[23], ws+W_F1O, ws+W_F2O, 700, 1000);
  fck   <<<48,  256, 0, stream>>>((const float*)d_in[24], (const float*)d_in[25], ws+W_F2O, (float*)d_out, 192, 700);
}

// Round 14
// 453.431 us; speedup vs baseline: 1.4846x; 1.4846x over previous
//
#include <hip/hip_runtime.h>

#define DEV __device__ __forceinline__

// ---- input plane sizes (complex element counts; imag plane at +PL) ----
#define PL_VU 12288
#define PL_UU 131072
#define PL_WU 8192
#define PL_GD 196608
#define PL_UD 16384
#define PL_WD 8192
#define PL_Z  196608
#define PL_HU 262144
#define PL_HD 262144
#define PL_P  16384
#define PL_GU 196608
#define PL_F  131072
#define PL_VD 12288
#define PL_J  4194304

// ---- intermediate plane sizes ----
#define SP_T   98304    // [96,8,128]
#define SP_PPH 32768    // [16,16,128]
#define SP_Q   196608   // [96,16,128] / [16,96,128]
#define SP_H2  262144   // [128,16,128]

// ---- workspace float offsets. complex buf: re at off+idx, im at off+plane+idx ----
#define W_T1   0
#define W_T2   196608
#define W_T3   393216
#define W_PPH  589824
#define W_VF   655360
#define W_M1   851968
#define W_M1C  1048576
#define W_M2   1245184
#define W_M2C  1441792
#define W_M3   1638400
#define W_QT   1835008
#define W_G2   2228224
#define W_H2   2621440
#define W_U2   3145728
#define W_TL   3538944
#define W_N1   3932160
#define W_R    4325376
#define W_MATS 4718592  // 9 x [2,96,96] (18432 each, plane 9216): A1,B1,C1,A2,B2,C2,A3,B3,C3
#define W_B11  4884480  // [96,128] pl 12288
#define W_B12  4909056  // [128,96] pl 12288
#define W_B21  4933632
#define W_B22  4958208
#define W_C1O  4982784  // 12*48*48
#define W_C2O  5010432  // 8*24*24
#define W_C3O  5015040  // 864
#define W_F1O  5015904  // 1000
#define W_F2O  5016904  // 700
// total 5017604 floats = 20.1 MB of d_ws

struct Ins {
  const float *VU,*UU,*WU,*GD,*UD,*WD,*Z,*HU,*HD,*P,*GU,*F,*VD,*J;
};

// =================== stage A: T1,T2,T3,PPH,VF ===================
// segments: T1 384, T2 384, T3 384, PPH 128, VF 384  => 1664 blocks
__global__ __launch_bounds__(256) void stageA(Ins in, float* __restrict__ ws) {
  int b = blockIdx.x, tid = threadIdx.x;
  if (b < 384) {                // T1[m,u,k] = sum_n conj(VU[n,m]) UU[n,u,k]
    int idx = b*256 + tid;
    int k = idx & 127, u = (idx >> 7) & 7, m = idx >> 10;
    float ar=0, ai=0;
    for (int n=0;n<128;++n) {
      float vr = in.VU[n*96+m], vi = in.VU[PL_VU+n*96+m];
      int iu = (n*8+u)*128+k;
      float ur = in.UU[iu], ui = in.UU[PL_UU+iu];
      ar += vr*ur + vi*ui; ai += vr*ui - vi*ur;
    }
    ws[W_T1+idx]=ar; ws[W_T1+SP_T+idx]=ai;
  } else if (b < 768) {         // T2[m,d,l] = sum_n conj(GD[n,m,l]) UD[n,d,l]
    int idx = (b-384)*256 + tid;
    int l = idx & 127, d = (idx >> 7) & 7, m = idx >> 10;
    float ar=0, ai=0;
    for (int n=0;n<16;++n) {
      int ig = (n*96+m)*128+l, iu = (n*8+d)*128+l;
      float gr = in.GD[ig], gi = in.GD[PL_GD+ig];
      float ur = in.UD[iu], ui = in.UD[PL_UD+iu];
      ar += gr*ur + gi*ui; ai += gr*ui - gi*ur;
    }
    ws[W_T2+idx]=ar; ws[W_T2+SP_T+idx]=ai;
  } else if (b < 1152) {        // T3 = same with Z
    int idx = (b-768)*256 + tid;
    int l = idx & 127, d = (idx >> 7) & 7, m = idx >> 10;
    float ar=0, ai=0;
    for (int n=0;n<16;++n) {
      int ig = (n*96+m)*128+l, iu = (n*8+d)*128+l;
      float gr = in.Z[ig], gi = in.Z[PL_Z+ig];
      float ur = in.UD[iu], ui = in.UD[PL_UD+iu];
      ar += gr*ur + gi*ui; ai += gr*ui - gi*ur;
    }
    ws[W_T3+idx]=ar; ws[W_T3+SP_T+idx]=ai;
  } else if (b < 1280) {        // PPH[a,b,k] = sum_u P[a,u,k] conj(P[b,u,k])
    int idx = (b-1152)*256 + tid;
    int k = idx & 127, bb = (idx >> 7) & 15, a = idx >> 11;
    float ar=0, ai=0;
    for (int u=0;u<8;++u) {
      int ia = (a*8+u)*128+k, ib = (bb*8+u)*128+k;
      float pr = in.P[ia], pi = in.P[PL_P+ia];
      float qr = in.P[ib], qi = in.P[PL_P+ib];
      ar += pr*qr + pi*qi; ai += pi*qr - pr*qi;
    }
    ws[W_PPH+idx]=ar; ws[W_PPH+SP_PPH+idx]=ai;
  } else {                      // VF[f,d,l] = sum_a VD[f,a] F[a,d,l]
    int idx = (b-1280)*256 + tid;
    int l = idx & 127, d = (idx >> 7) & 7, f = idx >> 10;
    float ar=0, ai=0;
    for (int a=0;a<128;++a) {
      float vr = in.VD[f*128+a], vi = in.VD[PL_VD+f*128+a];
      int ix = (a*8+d)*128+l;
      float fr = in.F[ix], fi = in.F[PL_F+ix];
      ar += vr*fr - vi*fi; ai += vr*fi + vi*fr;
    }
    ws[W_VF+idx]=ar; ws[W_VF+SP_T+idx]=ai;
  }
}

// ============ generic per-k inner product: out[m,n,k]=sum_e opA(A[m,e,k])*opB(B[..]) ============
template<bool CONJA, bool CONJB, bool BENK, int N, int E>
DEV void inner_seg(const float* __restrict__ A, int Apl,
                   const float* __restrict__ B, int Bpl,
                   float* __restrict__ O, int Opl, int idx) {
  int k = idx & 127;
  int n = (idx >> 7) % N;
  int m = idx / (128*N);
  float ar=0, ai=0;
  #pragma unroll
  for (int e=0;e<E;++e) {
    int ia = (m*E+e)*128+k;
    float xr = A[ia], xi = A[Apl+ia];
    if (CONJA) xi = -xi;
    int ib = BENK ? (e*N+n)*128+k : (n*E+e)*128+k;
    float yr = B[ib], yi = B[Bpl+ib];
    if (CONJB) yi = -yi;
    ar += xr*yr - xi*yi; ai += xr*yi + xi*yr;
  }
  O[idx]=ar; O[Opl+idx]=ai;
}

// =================== stage B: M1,M1c,M2,M2c,M3,Qt,G2,H2 + zero R ===================
// segments: 5x384 (M*), 768 (Qt), 768 (G2), 1024 (H2), 384 (zeroR) => 4864 blocks
__global__ __launch_bounds__(256) void stageB(Ins in, float* __restrict__ ws) {
  int b = blockIdx.x, tid = threadIdx.x;
  if (b < 384)       inner_seg<false,false,true ,8, 8>(ws+W_T1,SP_T, in.WU,PL_WU, ws+W_M1, SP_T, b*256+tid);
  else if (b < 768)  inner_seg<false,true ,false,8, 8>(ws+W_T1,SP_T, in.WU,PL_WU, ws+W_M1C,SP_T, (b-384)*256+tid);
  else if (b < 1152) inner_seg<false,false,true ,8, 8>(ws+W_T2,SP_T, in.WD,PL_WD, ws+W_M2, SP_T, (b-768)*256+tid);
  else if (b < 1536) inner_seg<false,true ,false,8, 8>(ws+W_T2,SP_T, in.WD,PL_WD, ws+W_M2C,SP_T, (b-1152)*256+tid);
  else if (b < 1920) inner_seg<false,false,true ,8, 8>(ws+W_T3,SP_T, in.WD,PL_WD, ws+W_M3, SP_T, (b-1536)*256+tid);
  else if (b < 2688) inner_seg<true ,false,false,16,16>(in.GU,PL_GU, ws+W_PPH,SP_PPH, ws+W_QT, SP_Q,  (b-1920)*256+tid);  // Qt[f,a,k]
  else if (b < 3456) inner_seg<false,true ,false,16,16>(in.GU,PL_GU, ws+W_PPH,SP_PPH, ws+W_G2, SP_Q,  (b-2688)*256+tid);  // G2[f,b,k] (PPH Hermitian)
  else if (b < 4480) inner_seg<false,true ,false,16,16>(in.HU,PL_HU, ws+W_PPH,SP_PPH, ws+W_H2, SP_H2, (b-3456)*256+tid);  // H2[n,b,k]
  else {  // zero R region (ws is poisoned 0xAA before every call; kR accumulates with atomics)
    int idx = (b-4480)*256 + tid;
    ((float4*)(ws+W_R))[idx] = make_float4(0.f,0.f,0.f,0.f);
  }
}

// =================== stage C: U2, TL, N1 ===================
__global__ __launch_bounds__(256) void stageC(float* __restrict__ ws, Ins in) {
  int b = blockIdx.x, tid = threadIdx.x;
  if (b < 768)        inner_seg<false,true,false,16,8>(ws+W_M2, SP_T, in.UD,PL_UD, ws+W_U2, SP_Q, b*256+tid);
  else if (b < 1536)  inner_seg<false,true,false,16,8>(ws+W_M3, SP_T, in.UD,PL_UD, ws+W_TL, SP_Q, (b-768)*256+tid);
  else                inner_seg<false,true,false,16,8>(ws+W_M1C,SP_T, in.P, PL_P,  ws+W_N1, SP_Q, (b-1536)*256+tid);
}

// =================== kR: R[n,f,l] = sum_{a,k} J[n,a,k,l] * Qt[f,a,k] ===================
// v5. grid 1024 = 16 n x 8 kc(16 k) x 2 lh(64 l) x 2 ah(8 a) x 2 fh(48 f);
// block 256 = 8 g-groups(6 f) x 32 lanes(2 l).
// Live-set redesign after v3/v4 spilled (round-8/10: acc spilled in hot loop, 0.7-1.2 GB scratch):
//   acc 24 (6f x 2l complex) + J dbuf 32 (2x(4+4) float2) + float4 staging ~12 + misc ~20 = ~92 < 128.
// Qt tile per a: 48f x 16k staged as float4 (384 slots, 1.5 loads/thread); LDS 2x6KB double-buffered.
__global__ __launch_bounds__(256, 2) void kR(Ins in, float* __restrict__ ws) {
  int bid = blockIdx.x;
  int n  = bid >> 6;
  int kc = (bid >> 3) & 7;
  int lh = (bid >> 2) & 1;
  int ah = (bid >> 1) & 1;
  int fh = bid & 1;
  int tid = threadIdx.x;
  int g    = tid >> 5;            // f-group 0..7 (6 f each)
  int lane = tid & 31;
  int l0 = lh*64 + lane*2;
  int k0 = kc*16;
  int a0 = ah*8;
  int fbase = fh*48;

  __shared__ float qt[2][1536];   // [buf][re: fl*16+kk | im: 768 + fl*16+kk], 12 KB

  float accr[6][2], acci[6][2];
  #pragma unroll
  for (int j=0;j<6;++j) { accr[j][0]=accr[j][1]=acci[j][0]=acci[j][1]=0.f; }

  const float* Jn = in.J + n*262144 + k0*128 + l0;
  float2 jrA[4], jiA[4], jrB[4], jiB[4];

// step s in [0,32): a = a0 + (s>>2), kk-chunk c = s&3 (4 kk per chunk, offset c*512)
#define LOADJ(JR, JI, s) { const float* Jb = Jn + (a0 + ((s)>>2))*16384 + ((s)&3)*512; \
  _Pragma("unroll") for (int kk=0;kk<4;++kk) { \
    JR[kk] = *(const float2*)(Jb + kk*128); \
    JI[kk] = *(const float2*)(Jb + PL_J + kk*128); } }

// stage Qt[fbase..fbase+48][a][k0..k0+16] as float4: 384 slots (192 re + 192 im)
#define STAGEQ(buf, a) { for (int s = tid; s < 384; s += 256) { \
    int plane = s / 192, r = s - plane*192; \
    int fl = r >> 2, kq = r & 3; \
    float4 v = *(const float4*)&ws[W_QT + plane*SP_Q + ((fbase+fl)*16 + (a))*128 + k0 + kq*4]; \
    *(float4*)&qt[buf][plane*768 + fl*16 + kq*4] = v; } }

#define COMPUTE(JR, JI, CUR, C) { _Pragma("unroll") for (int kk=0;kk<4;++kk) { \
    _Pragma("unroll") for (int j=0;j<6;++j) { \
      int qo = (g*6+j)*16 + (C)*4 + kk; \
      float qr = qt[CUR][qo], qi2 = qt[CUR][768 + qo]; \
      accr[j][0] += JR[kk].x*qr - JI[kk].x*qi2; \
      acci[j][0] += JR[kk].x*qi2 + JI[kk].x*qr; \
      accr[j][1] += JR[kk].y*qr - JI[kk].y*qi2; \
      acci[j][1] += JR[kk].y*qi2 + JI[kk].y*qr; } } }

  STAGEQ(0, a0)
  LOADJ(jrA, jiA, 0)
  for (int ia=0; ia<8; ++ia) {
    int cur = ia & 1;
    int s0 = ia*4;
    __syncthreads();                 // qt[cur] staged; fences overwrite of qt[cur^1] below
    if (ia < 7) STAGEQ(cur^1, a0+ia+1)
    LOADJ(jrB, jiB, s0+1)
    COMPUTE(jrA, jiA, cur, 0)
    LOADJ(jrA, jiA, s0+2)
    COMPUTE(jrB, jiB, cur, 1)
    LOADJ(jrB, jiB, s0+3)
    COMPUTE(jrA, jiA, cur, 2)
    if (ia < 7) LOADJ(jrA, jiA, s0+4)
    COMPUTE(jrB, jiB, cur, 3)
  }

  #pragma unroll
  for (int j=0;j<6;++j) {
    int f = fbase + g*6 + j;
    int o = (n*96+f)*128 + l0;
    atomicAdd(&ws[W_R + o],            accr[j][0]);
    atomicAdd(&ws[W_R + o + 1],        accr[j][1]);
    atomicAdd(&ws[W_R + SP_Q + o],     acci[j][0]);
    atomicAdd(&ws[W_R + SP_Q + o + 1], acci[j][1]);
  }
#undef LOADJ
#undef STAGEQ
#undef COMPUTE
}

// ============ generic flat contraction: C[i,j] = scale*sum_{o,c} A[i,o,c]*opB(B) ============
template<bool CONJB, bool OJC>
DEV void outer_tile(const float* __restrict__ A, int Apl,
                    const float* __restrict__ B, int Bpl,
                    float* __restrict__ C, int Cpl,
                    int J, int O, float scale, int tile) {
  __shared__ float As[16][33], Aip[16][33], Bs[16][33], Bip[16][33];
  int tj = J >> 4;
  int ti_ = tile / tj, tj_ = tile % tj;
  int tx = threadIdx.x & 15, ty = threadIdx.x >> 4;
  float ar=0, ai=0;
  int r0 = threadIdx.x >> 5, c = threadIdx.x & 31;
  for (int o=0;o<O;++o) {
    for (int cc=0;cc<128;cc+=32) {
      __syncthreads();
      #pragma unroll
      for (int rr=r0; rr<16; rr+=8) {
        int aidx = ((ti_*16+rr)*O+o)*128+cc+c;
        As[rr][c]=A[aidx]; Aip[rr][c]=A[Apl+aidx];
        int brow = tj_*16+rr;
        int bidx = OJC ? (o*J+brow)*128+cc+c : (brow*O+o)*128+cc+c;
        Bs[rr][c]=B[bidx]; Bip[rr][c]=B[Bpl+bidx];
      }
      __syncthreads();
      #pragma unroll
      for (int q=0;q<32;++q) {
        float xr=As[ty][q], xi=Aip[ty][q];
        float yr=Bs[tx][q], yi=Bip[tx][q];
        if (CONJB) { ar += xr*yr + xi*yi; ai += xi*yr - xr*yi; }
        else       { ar += xr*yr - xi*yi; ai += xr*yi + xi*yr; }
      }
    }
  }
  int i = ti_*16+ty, j = tj_*16+tx;
  C[i*J+j] = scale*ar; C[Cpl+i*J+j] = scale*ai;
}

// =================== stage D: all flat contractions (516 blocks) ===================
__global__ __launch_bounds__(256) void stageD(Ins in, float* __restrict__ ws) {
  int b = blockIdx.x;
  if (b < 36)        outer_tile<true ,false>(ws+W_M1, SP_T,  ws+W_T1, SP_T,  ws+W_MATS+0*18432, 9216, 96, 8,  1.f, b);      // A1
  else if (b < 72)   outer_tile<true ,false>(ws+W_M2, SP_T,  ws+W_T2, SP_T,  ws+W_MATS+3*18432, 9216, 96, 8,  1.f, b-36);   // A2
  else if (b < 108)  outer_tile<true ,false>(ws+W_M3, SP_T,  ws+W_T3, SP_T,  ws+W_MATS+6*18432, 9216, 96, 8,  1.f, b-72);   // A3
  else if (b < 144)  outer_tile<true ,false>(ws+W_G2, SP_Q,  in.GU,   PL_GU, ws+W_MATS+2*18432, 9216, 96, 16, 1.f, b-108);  // C1
  else if (b < 180)  outer_tile<true ,false>(ws+W_G2, SP_Q,  in.GU,   PL_GU, ws+W_MATS+8*18432, 9216, 96, 16, 1.f, b-144);  // C3=C1
  else if (b < 216)  outer_tile<true ,false>(ws+W_VF, SP_T,  ws+W_VF, SP_T,  ws+W_MATS+5*18432, 9216, 96, 8,  1.f, b-180);  // C2
  else if (b < 264)  outer_tile<true ,false>(ws+W_M1, SP_T,  in.UU,   PL_UU, ws+W_B11, 12288, 128, 8,  1.f, b-216);         // B1_1[m,n]
  else if (b < 312)  outer_tile<true ,false>(ws+W_H2, SP_H2, in.GU,   PL_GU, ws+W_B12, 12288,  96, 16, 1.f, b-264);         // B1_2[n,f]
  else if (b < 348)  outer_tile<true ,false>(ws+W_N1, SP_Q,  in.GU,   PL_GU, ws+W_MATS+1*18432, 9216, 96, 16, 1.f, b-312);  // B1_3 (pre for B1)
  else if (b < 396)  outer_tile<false,true >(ws+W_U2, SP_Q,  in.HD,   PL_HD, ws+W_B21, 12288, 128, 16, 1.f, b-348);         // B2_1[m,t]
  else if (b < 444)  outer_tile<true ,false>(in.F,    PL_F,  ws+W_VF, SP_T,  ws+W_B22, 12288,  96, 8,  1.f, b-396);         // B2_2[a,f]
  else if (b < 480)  outer_tile<true ,false>(ws+W_M2C,SP_T,  ws+W_VF, SP_T,  ws+W_MATS+4*18432, 9216, 96, 8,  1.f, b-444);  // B2_3 (pre for B2)
  else               outer_tile<false,true >(ws+W_TL, SP_Q,  ws+W_R,  SP_Q,  ws+W_MATS+7*18432, 9216, 96, 16,-1.f, b-480);  // B3
}

// =================== stage E: B1 = B1_3 - B1_1@B1_2 ; B2 = B2_3 - B2_1@B2_2 ===================
__global__ __launch_bounds__(256) void stageE(float* __restrict__ ws) {
  int idx = blockIdx.x*256 + threadIdx.x;
  int seg = idx / 9216;
  int t = idx % 9216;
  int m = t / 96, f = t % 96;
  const float* A = ws + (seg ? W_B21 : W_B11);
  const float* B = ws + (seg ? W_B22 : W_B12);
  float* C = ws + W_MATS + (seg ? 4 : 1)*18432;
  float ar = C[t], ai = C[9216+t];
  for (int n=0;n<128;++n) {
    float xr = A[m*128+n], xi = A[12288+m*128+n];
    float yr = B[n*96+f],  yi = B[12288+n*96+f];
    ar -= xr*yr - xi*yi;
    ai -= xr*yi + xi*yr;
  }
  C[t] = ar; C[9216+t] = ai;
}

// =================== conv (2x2, stride 2, relu) ===================
__global__ __launch_bounds__(256) void convk(const float* __restrict__ x, const float* __restrict__ w,
                      const float* __restrict__ bias, float* __restrict__ out,
                      int IC, int IW, int OC, int OW) {
  int idx = blockIdx.x*256 + threadIdx.x;
  int total = OC*OW*OW;
  if (idx >= total) return;
  int ow = idx % OW, oh = (idx/OW) % OW, oc = idx/(OW*OW);
  float acc = bias[oc];
  const float* wk = w + oc*IC*4;
  for (int ic=0; ic<IC; ++ic) {
    const float* xp = x + ic*IW*IW + (oh*2)*IW + ow*2;
    acc += xp[0]*wk[0] + xp[1]*wk[1] + xp[IW]*wk[2] + xp[IW+1]*wk[3];
    wk += 4;
  }
  out[idx] = fmaxf(acc, 0.f);
}

// =================== fc (wave per output, relu) ===================
__global__ __launch_bounds__(256) void fck(const float* __restrict__ W, const float* __restrict__ b,
                    const float* __restrict__ x, float* __restrict__ out,
                    int nout, int nin) {
  int wave = (blockIdx.x*256 + threadIdx.x) >> 6;
  int lane = threadIdx.x & 63;
  if (wave >= nout) return;
  float acc = 0.f;
  const float* Wr = W + (long)wave*nin;
  for (int c = lane; c < nin; c += 64) acc += Wr[c]*x[c];
  #pragma unroll
  for (int off=32; off; off>>=1) acc += __shfl_down(acc, off, 64);
  if (lane==0) out[wave] = fmaxf(acc + b[wave], 0.f);
}

extern "C" void kernel_launch(void* const* d_in, const int* in_sizes, int n_in,
                              void* d_out, int out_size, void* d_ws, size_t ws_size,
                              hipStream_t stream) {
  Ins in;
  in.VU=(const float*)d_in[0];  in.UU=(const float*)d_in[1];  in.WU=(const float*)d_in[2];
  in.GD=(const float*)d_in[3];  in.UD=(const float*)d_in[4];  in.WD=(const float*)d_in[5];
  in.Z =(const float*)d_in[6];  in.HU=(const float*)d_in[7];  in.HD=(const float*)d_in[8];
  in.P =(const float*)d_in[9];  in.GU=(const float*)d_in[10]; in.F =(const float*)d_in[11];
  in.VD=(const float*)d_in[12]; in.J =(const float*)d_in[13];
  float* ws = (float*)d_ws;

  stageA<<<1664,256, 0, stream>>>(in, ws);
  stageB<<<4864,256, 0, stream>>>(in, ws);
  stageC<<<2304,256, 0, stream>>>(ws, in);
  kR    <<<1024,256, 0, stream>>>(in, ws);
  stageD<<<516, 256, 0, stream>>>(in, ws);
  stageE<<<72,  256, 0, stream>>>(ws);
  convk <<<108, 256, 0, stream>>>(ws+W_MATS, (const float*)d_in[14], (const float*)d_in[15], ws+W_C1O, 18, 96, 12, 48);
  convk <<<18,  256, 0, stream>>>(ws+W_C1O,  (const float*)d_in[16], (const float*)d_in[17], ws+W_C2O, 12, 48, 8, 24);
  convk <<<4,   256, 0, stream>>>(ws+W_C2O,  (const float*)d_in[18], (const float*)d_in[19], ws+W_C3O, 8, 24, 6, 12);
  fck   <<<250, 256, 0, stream>>>((const float*)d_in[20], (const float*)d_in[21], ws+W_C3O, ws+W_F1O, 1000, 864);
  fck   <<<175, 256, 0, stream>>>((const float*)d_in[22], (const float*)d_in[23], ws+W_F1O, ws+W_F2O, 700, 1000);
  fck   <<<48,  256, 0, stream>>>((const float*)d_in[24], (const float*)d_in[25], ws+W_F2O, (float*)d_out, 192, 700);
}